// Round 1
// baseline (14312.546 us; speedup 1.0000x reference)
//
#include <hip/hip_runtime.h>
#include <math.h>

// Problem constants (from reference setup_inputs)
#define BB 64      // batch
#define TT 512     // time steps
#define DD 256     // input dim
#define HH 512     // hidden dim
#define GG 2048    // 4*H gate width
#define KX 768     // D+H concat K dim
#define CTXF 49152 // context_state floats (B * KX) — traj_h starts after this

// ---------------------------------------------------------------------------
// pack VU^T: vut[k][j] = j<D ? W[j][k] : U[j-D][k]   (k in [0,2048), j in [0,768))
// LDS-tiled transpose, 32x32 tiles.
// ---------------------------------------------------------------------------
__global__ void pack_vut(const float* __restrict__ Wm, const float* __restrict__ Um,
                         float* __restrict__ vut) {
    __shared__ float tile[32][33];
    int k0 = blockIdx.x * 32;   // gate-column block
    int j0 = blockIdx.y * 32;   // K block
    int lx = threadIdx.x & 31;
    int ly = threadIdx.x >> 5;  // 8 rows per pass
    for (int r = ly; r < 32; r += 8) {
        int j = j0 + r, k = k0 + lx;
        tile[r][lx] = (j < DD) ? Wm[j * GG + k] : Um[(j - DD) * GG + k];
    }
    __syncthreads();
    for (int r = ly; r < 32; r += 8) {
        int k = k0 + r, j = j0 + lx;
        vut[(long)k * KX + j] = tile[lx][r];
    }
}

// ---------------------------------------------------------------------------
// zero h double-buffer + c state
// ---------------------------------------------------------------------------
__global__ void init_state(float* __restrict__ h, float* __restrict__ c) {
    int idx = blockIdx.x * 256 + threadIdx.x;
    if (idx < 2 * BB * HH) h[idx] = 0.f;
    if (idx < BB * HH) c[idx] = 0.f;
}

// ---------------------------------------------------------------------------
// copy x into traj_h[:, :, 0:256] and context_state[:, 0:256]
// ---------------------------------------------------------------------------
__global__ void xcopy(const float* __restrict__ x, float* __restrict__ out) {
    const long n_traj = (long)BB * TT * (DD / 4); // 2,097,152 float4
    long idx = (long)blockIdx.x * 256 + threadIdx.x;
    const float4* x4 = (const float4*)x;
    float4* out4 = (float4*)out;
    if (idx < n_traj) {
        long bt = idx / (DD / 4);
        int d4 = (int)(idx % (DD / 4));
        out4[(CTXF / 4) + bt * (KX / 4) + d4] = x4[idx];
    } else if (idx < n_traj + BB * (DD / 4)) {
        long f = idx - n_traj;
        int b = (int)(f / (DD / 4)), d4 = (int)(f % (DD / 4));
        out4[(long)b * (KX / 4) + d4] = x4[((long)b * TT + (TT - 1)) * (DD / 4) + d4];
    }
}

// ---------------------------------------------------------------------------
// One LSTM step.  Grid: (64 j-slices, 4 batch-groups), block 256.
// WG owns batches [b0,b0+16) and j in [j0,j0+8) — i.e. gate columns
// {j, j+512, j+1024, j+1536} so the c/h update is WG-local.
// ---------------------------------------------------------------------------
#define BM 16
#define JS 8

__global__ __launch_bounds__(256) void lstm_step(
    const float* __restrict__ vut, const float* __restrict__ bias,
    const float* __restrict__ x, const float* __restrict__ hprev,
    float* __restrict__ hnext, float* __restrict__ c,
    float* __restrict__ out, int t)
{
    __shared__ float xh[BM][KX];   // 48 KB: [x_t | h] for 16 batches
    __shared__ float zs[BM][32];   // z staging for gate combine

    const int jb = blockIdx.x;     // 0..63
    const int bg = blockIdx.y;     // 0..3
    const int b0 = bg * BM;
    const int j0 = jb * JS;
    const int tid = threadIdx.x;

    // ---- stage xh = [x[:,t,:], hprev] into LDS (coalesced float4) ----
    for (int i = tid; i < BM * (DD / 4); i += 256) {
        int bb = i >> 6, d4 = i & 63;
        float4 v = ((const float4*)x)[((long)((b0 + bb) * TT + t)) * (DD / 4) + d4];
        ((float4*)&xh[bb][0])[d4] = v;
    }
    for (int i = tid; i < BM * (HH / 4); i += 256) {
        int bb = i >> 7, j4 = i & 127;
        float4 v = ((const float4*)hprev)[(b0 + bb) * (HH / 4) + j4];
        ((float4*)&xh[bb][DD])[j4] = v;
    }
    __syncthreads();

    // ---- dot products: each thread owns column k for 2 batches ----
    const int klocal = tid & 31;       // 0..31 -> gate*8 + jj
    const int blocal = tid >> 5;       // 0..7
    const int gate = klocal >> 3;
    const int jj = klocal & 7;
    const int k = gate * HH + j0 + jj; // global gate column

    const float4* vrow = (const float4*)(vut + (long)k * KX);
    const float4* xa = (const float4*)&xh[blocal][0];
    const float4* xb = (const float4*)&xh[blocal + 8][0];

    // split accumulators to break FMA dependency chains
    float a0x = bias[k], a0y = 0.f, a0z = 0.f, a0w = 0.f;
    float a1x = bias[k], a1y = 0.f, a1z = 0.f, a1w = 0.f;
    #pragma unroll 8
    for (int j4 = 0; j4 < KX / 4; ++j4) {
        float4 w = vrow[j4];
        float4 p = xa[j4];
        float4 q = xb[j4];
        a0x += w.x * p.x; a0y += w.y * p.y; a0z += w.z * p.z; a0w += w.w * p.w;
        a1x += w.x * q.x; a1y += w.y * q.y; a1z += w.z * q.z; a1w += w.w * q.w;
    }
    zs[blocal][klocal] = (a0x + a0y) + (a0z + a0w);
    zs[blocal + 8][klocal] = (a1x + a1y) + (a1z + a1w);
    __syncthreads();

    // ---- gate combine + state update (threads with klocal<8 active) ----
    if (klocal < JS) {
        #pragma unroll
        for (int s = 0; s < 2; ++s) {
            int bb = blocal + s * 8;
            float iv = tanhf(zs[bb][jj]);
            float fv = tanhf(zs[bb][8 + jj]);
            float gv = tanhf(zs[bb][16 + jj]);
            float ov = tanhf(zs[bb][24 + jj]);
            int b = b0 + bb, j = j0 + jj;
            float cprev = c[b * HH + j];
            float c2 = fv * cprev + iv * gv;
            float h2 = ov * tanhf(c2);
            c[b * HH + j] = c2;
            hnext[b * HH + j] = h2;
            out[CTXF + ((long)(b * TT + t)) * KX + DD + j] = h2;
            if (t == TT - 1) out[(long)b * KX + DD + j] = h2;  // context h-part
        }
    }
}

// ---------------------------------------------------------------------------
extern "C" void kernel_launch(void* const* d_in, const int* in_sizes, int n_in,
                              void* d_out, int out_size, void* d_ws, size_t ws_size,
                              hipStream_t stream) {
    (void)in_sizes; (void)n_in; (void)out_size; (void)ws_size;
    const float* x    = (const float*)d_in[0];
    const float* Wm   = (const float*)d_in[1];
    const float* Um   = (const float*)d_in[2];
    const float* bias = (const float*)d_in[3];
    float* out = (float*)d_out;
    float* ws  = (float*)d_ws;

    float* vut = ws;                       // 2048*768 = 1,572,864 floats
    float* h   = ws + 1572864;             // 2 * 64*512 = 65,536 floats
    float* c   = ws + 1572864 + 65536;     // 32,768 floats

    hipLaunchKernelGGL(pack_vut, dim3(64, 24), dim3(256), 0, stream, Wm, Um, vut);
    hipLaunchKernelGGL(init_state, dim3(256), dim3(256), 0, stream, h, c);
    hipLaunchKernelGGL(xcopy, dim3(8209), dim3(256), 0, stream, x, out);

    for (int t = 0; t < TT; ++t) {
        const float* hp = h + (t & 1) * (BB * HH);
        float* hn       = h + ((t + 1) & 1) * (BB * HH);
        hipLaunchKernelGGL(lstm_step, dim3(64, 4), dim3(256), 0, stream,
                           vut, bias, x, hp, hn, c, out, t);
    }
}